// Round 1
// baseline (236.170 us; speedup 1.0000x reference)
//
#include <hip/hip_runtime.h>

// bMomentumLIF forward: x[B,T,F] fp32 -> spikes[B,T,F] fp32
// Recurrence per neuron (b,f) over t:
//   u  = u_last * 0.5 + x[t]            (TAU=2, /2 == *0.5 exactly)
//   s  = (u - th >= 0) ? 1 : 0
//   m  = mt*m + (1-mt)*(u - u_last)
//   u' = (u*lb + m*(1-lb)) * (1-s)
// Memory-bound: 128 MiB in + 128 MiB out -> ~43 us floor @ 6.3 TB/s.

constexpr int B  = 64;
constexpr int T  = 64;
constexpr int F  = 8192;
constexpr int F4 = F / 4;   // float4 granularity along F

__global__ __launch_bounds__(256) void lif_fwd_kernel(
    const float4* __restrict__ x,
    const float*  __restrict__ momentum,
    const float*  __restrict__ lamb,
    const float*  __restrict__ thresholds,
    float4*       __restrict__ out)
{
    // Disable FMA contraction: spike threshold is exact-compare against the
    // numpy fp32 reference; contraction changes rounding of the m-update and
    // can flip spikes at the boundary (error 1.0).
#pragma clang fp contract(off)

    const int tid = blockIdx.x * blockDim.x + threadIdx.x;   // 0 .. B*F4-1
    const int b   = tid / F4;
    const int f4  = tid - b * F4;

    const float mt  = momentum[0];
    const float omt = 1.0f - mt;
    const float lb  = lamb[0];
    const float olb = 1.0f - lb;
    const float th  = thresholds[0];

    int idx = b * (T * F4) + f4;   // float4 index; stride F4 per timestep

    float u0 = 0.0f, u1 = 0.0f, u2 = 0.0f, u3 = 0.0f;
    float m0 = 0.0f, m1 = 0.0f, m2 = 0.0f, m3 = 0.0f;

#pragma unroll
    for (int t = 0; t < T; ++t) {
        const float4 xi = x[idx];
        float4 sv;

        // component 0
        {
            const float u  = u0 * 0.5f + xi.x;
            const float s  = ((u - th) >= 0.0f) ? 1.0f : 0.0f;
            const float a  = mt * m0;
            const float bq = omt * (u - u0);
            m0 = a + bq;
            u0 = (u * lb + m0 * olb) * (1.0f - s);
            sv.x = s;
        }
        // component 1
        {
            const float u  = u1 * 0.5f + xi.y;
            const float s  = ((u - th) >= 0.0f) ? 1.0f : 0.0f;
            const float a  = mt * m1;
            const float bq = omt * (u - u1);
            m1 = a + bq;
            u1 = (u * lb + m1 * olb) * (1.0f - s);
            sv.y = s;
        }
        // component 2
        {
            const float u  = u2 * 0.5f + xi.z;
            const float s  = ((u - th) >= 0.0f) ? 1.0f : 0.0f;
            const float a  = mt * m2;
            const float bq = omt * (u - u2);
            m2 = a + bq;
            u2 = (u * lb + m2 * olb) * (1.0f - s);
            sv.z = s;
        }
        // component 3
        {
            const float u  = u3 * 0.5f + xi.w;
            const float s  = ((u - th) >= 0.0f) ? 1.0f : 0.0f;
            const float a  = mt * m3;
            const float bq = omt * (u - u3);
            m3 = a + bq;
            u3 = (u * lb + m3 * olb) * (1.0f - s);
            sv.w = s;
        }

        out[idx] = sv;
        idx += F4;
    }
}

extern "C" void kernel_launch(void* const* d_in, const int* in_sizes, int n_in,
                              void* d_out, int out_size, void* d_ws, size_t ws_size,
                              hipStream_t stream) {
    const float4* x   = (const float4*)d_in[0];
    const float*  mom = (const float*)d_in[1];
    const float*  lmb = (const float*)d_in[2];
    const float*  thr = (const float*)d_in[3];
    float4* out = (float4*)d_out;

    const int n_threads = B * F4;          // 131072
    const int block = 256;
    const int grid = n_threads / block;    // 512
    lif_fwd_kernel<<<grid, block, 0, stream>>>(x, mom, lmb, thr, out);
}